// Round 2
// 486.674 us; speedup vs baseline: 1.1391x; 1.1391x over previous
//
#include <hip/hip_runtime.h>

#define DIM 4096

typedef __bf16 bf16x8 __attribute__((ext_vector_type(8)));
typedef float floatx4 __attribute__((ext_vector_type(4)));

__device__ __forceinline__ void async_ld16(void* lds, const void* g) {
  __builtin_amdgcn_global_load_lds(
      (const __attribute__((address_space(1))) unsigned int*)g,
      (__attribute__((address_space(3))) unsigned int*)lds, 16, 0, 0);
}

// ---------------- kernel 1: fused build_small + build_k012 ----------------
// K012[abc=128][k=8][vwx=128]; K34T[k=8][yz=32][de=32]
// blocks 0..511: K012 (K01 slice recomputed per-block in LDS — abc fixed per block)
// blocks 512..543: K34T
__global__ void build_k(const float* __restrict__ c0, const float* __restrict__ c1,
                        const float* __restrict__ c2, const float* __restrict__ c3,
                        const float* __restrict__ c4,
                        float* __restrict__ K012, float* __restrict__ K34T) {
  const int bid = blockIdx.x, tid = threadIdx.x;
  if (bid < 512) {
    __shared__ float K01s[128];  // [j=8][vw=16] for this block's fixed ab
    const int abc = bid >> 2;    // t = bid*256+tid, abc = t>>10 = bid>>2 (fixed)
    const int ab = abc >> 3, c = abc & 7;
    if (tid < 128) {
      const int a = ab >> 2, b = ab & 3;
      const int j = tid >> 4, vw = tid & 15, v = vw >> 2, w = vw & 3;
      float s = 0.f;
#pragma unroll
      for (int i = 0; i < 8; ++i)
        s += c0[a * 32 + i * 4 + v] * c1[b * 256 + i * 32 + j * 4 + w];
      K01s[tid] = s;
    }
    __syncthreads();
    const int t = bid * 256 + tid;
    const int vwx = t & 127, k = (t >> 7) & 7;
    const int vw = vwx >> 3, xx = vwx & 7;
    float s = 0.f;
#pragma unroll
    for (int j = 0; j < 8; ++j)
      s += K01s[j * 16 + vw] * c2[c * 512 + j * 64 + k * 8 + xx];
    K012[t] = s;
  } else {
    const int u = (bid - 512) * 256 + tid;
    const int yz = u & 31, kk = (u >> 5) & 7, de = u >> 8;
    const int d = de >> 2, e = de & 3, y = yz >> 2, z = yz & 3;
    float s = 0.f;
#pragma unroll
    for (int l = 0; l < 8; ++l)
      s += c3[d * 512 + kk * 64 + l * 8 + y] * c4[e * 32 + l * 4 + z];
    K34T[kk * 1024 + yz * 32 + de] = s;
  }
}

// ---------------- kernel 2: fused build_wt (8 outs/thread) + x_to_bf16 ----------------
// WT[o=4096][in=4096] bf16, o = vwx*32+yz, in = abc*32+de
// blocks 0..8191: WT (each thread: 8 consecutive `in`, i.e. de0..de0+7, abc fixed)
// blocks 8192..24575: X fp32 -> bf16 (overlaps with WT build)
__global__ void build_wt_conv(const float* __restrict__ K012, const float* __restrict__ K34T,
                              __bf16* __restrict__ WT,
                              const float* __restrict__ X, __bf16* __restrict__ Xb) {
  const int bid = blockIdx.x, tid = threadIdx.x;
  if (bid < 8192) {
    const long t = (long)bid * 256 + tid;     // 2,097,152 threads
    const long e8 = t * 8;
    const int in = (int)(e8 & 4095), o = (int)(e8 >> 12);
    const int de0 = in & 31, abc = in >> 5;   // de0 in {0,8,16,24}
    const int yz = o & 31, vwx = o >> 5;
    const float* kp = K012 + abc * 1024 + vwx;
    const float* vp = K34T + yz * 32 + de0;
    float s[8] = {};
#pragma unroll
    for (int k = 0; k < 8; ++k) {
      const float a = kp[k * 128];
      const float4 v0 = *(const float4*)(vp + k * 1024);
      const float4 v1 = *(const float4*)(vp + k * 1024 + 4);
      s[0] += a * v0.x; s[1] += a * v0.y; s[2] += a * v0.z; s[3] += a * v0.w;
      s[4] += a * v1.x; s[5] += a * v1.y; s[6] += a * v1.z; s[7] += a * v1.w;
    }
    bf16x8 w;
#pragma unroll
    for (int d = 0; d < 8; ++d) w[d] = (__bf16)s[d];
    ((bf16x8*)WT)[t] = w;
  } else {
    const long t = (long)(bid - 8192) * 256 + tid;  // 4,194,304 threads
    const float4 a = ((const float4*)X)[t * 2];
    const float4 b = ((const float4*)X)[t * 2 + 1];
    bf16x8 w;
    w[0] = (__bf16)a.x; w[1] = (__bf16)a.y; w[2] = (__bf16)a.z; w[3] = (__bf16)a.w;
    w[4] = (__bf16)b.x; w[5] = (__bf16)b.y; w[6] = (__bf16)b.z; w[7] = (__bf16)b.w;
    ((bf16x8*)Xb)[t] = w;
  }
}

// ---------------- GEMM: 256x256 tile, BK=64, 8 waves, 8-phase counted-vmcnt ----------------
// C[8192][4096] = Xb * WT^T + bias.
// Waves: 2(M) x 4(N); wave owns 128x64 via interleaved frags:
//   m-frag f: rows (2f+wm)*16  -> f=0..3 in Ah0 (rows 0..127), f=4..7 in Ah1
//   n-frag g: rows (4g+wn)*16  -> g=0..1 in Bh0, g=2..3 in Bh1
// Half-tiles per K-tile: h0=Ah0, h1=Bh0, h2=Bh1, h3=Ah1. Tile t lives in buf t&1.
// Per phase: {ds_read frags | stage 1 half-tile} ; s_barrier ; lgkmcnt(0) ; sched_barrier ;
//            setprio(1) 16xMFMA setprio(0) ; s_barrier ; sched_barrier.
// vmcnt(6) only at end of phases 4 and 8 (3 half-tiles = 6 loads stay in flight).
// Stage schedule (iter computes tiles T=2k buf0, T+1 buf1):
//   ph1:(T+1).h3  ph2:(T+2).h0  ph3:(T+2).h1  ph4:(T+2).h2  [vmcnt(6)]
//   ph5:(T+2).h3  ph6:(T+3).h0  ph7:(T+3).h1  ph8:(T+3).h2  [vmcnt(6)]
// WAR safety: a slot's ds_reads happen in exactly one phase; reads drain (lgkmcnt(0))
// before that phase's closing s_barrier, and the overwriting stage is issued only
// after all waves pass that barrier (1-2 phases later).
// RAW safety: vmcnt(6) at ph4 retires the 8 oldest loads = all of tile T+1 before ph5;
// at ph8 retires all of tile T+2 before next iter's ph1.
// Tail iters: t2/t3 clamp to 63 -> stages rewrite identical tile-63 data into slots
// whose reads already drained; benign.
// XOR chunk swizzle: phys chunk pc at row r holds global chunk pc^(r&7)
// (pre-swizzled global source, linear LDS dest -> measured 0 bank conflicts).

#define G_BAR1() do { __builtin_amdgcn_s_barrier(); \
                      asm volatile("s_waitcnt lgkmcnt(0)" ::: "memory"); \
                      __builtin_amdgcn_sched_barrier(0); } while (0)
#define G_BAR2() do { __builtin_amdgcn_s_barrier(); \
                      __builtin_amdgcn_sched_barrier(0); } while (0)
#define G_VM6()  asm volatile("s_waitcnt vmcnt(6)" ::: "memory")

#define G_STA(p, h, koff) do { \
  async_ld16(&As[p][(h) * 128][0] + ldsq[0], agp[0] + (h) * 524288 + (koff)); \
  async_ld16(&As[p][(h) * 128][0] + ldsq[1], agp[1] + (h) * 524288 + (koff)); } while (0)
#define G_STB(p, h, koff) do { \
  async_ld16(&Bs[p][(h) * 128][0] + ldsq[0], bgp[0] + (h) * 524288 + (koff)); \
  async_ld16(&Bs[p][(h) * 128][0] + ldsq[1], bgp[1] + (h) * 524288 + (koff)); } while (0)

#define G_LDA(p, mh) do { \
  _Pragma("unroll") for (int fi = 0; fi < 4; ++fi) { \
    const int row = ((mh) * 8 + 2 * fi + wm) * 16 + lm; \
    _Pragma("unroll") for (int kh = 0; kh < 2; ++kh) \
      af[fi][kh] = *(const bf16x8*)&As[p][row][((kh * 4 + kq) ^ (row & 7)) * 8]; \
  } } while (0)
#define G_LDB(p, nh) do { \
  _Pragma("unroll") for (int gi = 0; gi < 2; ++gi) { \
    const int g = (nh) * 2 + gi; \
    const int row = (4 * g + wn) * 16 + lm; \
    _Pragma("unroll") for (int kh = 0; kh < 2; ++kh) \
      bfv[g][kh] = *(const bf16x8*)&Bs[p][row][((kh * 4 + kq) ^ (row & 7)) * 8]; \
  } } while (0)

#define G_MMA(mh, nh) do { \
  __builtin_amdgcn_s_setprio(1); \
  _Pragma("unroll") for (int fi = 0; fi < 4; ++fi) \
  _Pragma("unroll") for (int gi = 0; gi < 2; ++gi) \
  _Pragma("unroll") for (int kh = 0; kh < 2; ++kh) \
    acc[(mh) * 4 + fi][(nh) * 2 + gi] = __builtin_amdgcn_mfma_f32_16x16x32_bf16( \
        af[fi][kh], bfv[(nh) * 2 + gi][kh], acc[(mh) * 4 + fi][(nh) * 2 + gi], 0, 0, 0); \
  __builtin_amdgcn_s_setprio(0); } while (0)

__global__ __launch_bounds__(512, 2) void gemm_8ph(const __bf16* __restrict__ A,
                                                   const __bf16* __restrict__ WT,
                                                   const float* __restrict__ bias,
                                                   float* __restrict__ C) {
  __shared__ __bf16 As[2][256][64];
  __shared__ __bf16 Bs[2][256][64];

  const int tid = threadIdx.x;
  // XCD-aware swizzle: 512 blocks, 64 contiguous per XCD (n-fast: 16 blocks share an A panel)
  const int gb = (blockIdx.x & 7) * 64 + (blockIdx.x >> 3);
  const int m0 = (gb >> 4) * 256;
  const int n0 = (gb & 15) * 256;

  const int wave = tid >> 6, lane = tid & 63;
  const int wm = wave & 1, wn = wave >> 1;
  const int lm = lane & 15, kq = lane >> 4;

  floatx4 acc[8][4] = {};
  bf16x8 af[4][2], bfv[4][2];

  // staging: chunk q = tid + j*512; row r=q>>3 (0..127), phys chunk pc=q&7,
  // global chunk c = pc ^ (r&7). LDS dest is wave-uniform base + lane*16.
  const __bf16* agp[2];
  const __bf16* bgp[2];
  int ldsq[2];
#pragma unroll
  for (int j = 0; j < 2; ++j) {
    const int q = tid + j * 512;
    const int r = q >> 3, pc = q & 7;
    const int c = pc ^ (r & 7);
    ldsq[j] = q * 8;  // element offset within a half-tile
    agp[j] = A + (long)(m0 + r) * DIM + c * 8;
    bgp[j] = WT + (long)(n0 + r) * DIM + c * 8;
  }

  // prologue: tile0 (h0..h3) + tile1 (h0..h2); wait tile0 (8 of 14 loads), barrier
  G_STA(0, 0, 0); G_STB(0, 0, 0); G_STB(0, 1, 0); G_STA(0, 1, 0);
  G_STA(1, 0, 64); G_STB(1, 0, 64); G_STB(1, 1, 64);
  G_VM6();
  __builtin_amdgcn_s_barrier();
  __builtin_amdgcn_sched_barrier(0);

#pragma unroll 1
  for (int it = 0; it < 32; ++it) {
    const int kA = (2 * it + 1) * 64;                     // tile T+1 (always real)
    int t2 = 2 * it + 2; if (t2 > 63) t2 = 63;            // clamped: rewrite of dead slots
    int t3 = 2 * it + 3; if (t3 > 63) t3 = 63;
    const int kB = t2 * 64, kC = t3 * 64;

    // ---- tile T (buf0) ----
    G_LDA(0, 0); G_LDB(0, 0);       // ph1: 12 ds_reads
    G_STA(1, 1, kA);                //      (T+1).h3 -> buf1.Ah1 (read last at prev ph7)
    G_BAR1(); G_MMA(0, 0); G_BAR2();

    G_LDB(0, 1);                    // ph2
    G_STA(0, 0, kB);                //      (T+2).h0 -> buf0.Ah0 (read in ph1)
    G_BAR1(); G_MMA(0, 1); G_BAR2();

    G_LDA(0, 1);                    // ph3
    G_STB(0, 0, kB);                //      (T+2).h1 -> buf0.Bh0 (read in ph1)
    G_BAR1(); G_MMA(1, 0); G_BAR2();

    G_STB(0, 1, kB);                // ph4: (T+2).h2 -> buf0.Bh1 (read in ph2)
    G_BAR1(); G_MMA(1, 1);
    G_VM6();                        // tile T+1 fully landed
    G_BAR2();

    // ---- tile T+1 (buf1) ----
    G_LDA(1, 0); G_LDB(1, 0);       // ph5
    G_STA(0, 1, kB);                //      (T+2).h3 -> buf0.Ah1 (read in ph3)
    G_BAR1(); G_MMA(0, 0); G_BAR2();

    G_LDB(1, 1);                    // ph6
    G_STA(1, 0, kC);                //      (T+3).h0 -> buf1.Ah0 (read in ph5)
    G_BAR1(); G_MMA(0, 1); G_BAR2();

    G_LDA(1, 1);                    // ph7
    G_STB(1, 0, kC);                //      (T+3).h1 -> buf1.Bh0 (read in ph5)
    G_BAR1(); G_MMA(1, 0); G_BAR2();

    G_STB(1, 1, kC);                // ph8: (T+3).h2 -> buf1.Bh1 (read in ph6)
    G_BAR1(); G_MMA(1, 1);
    G_VM6();                        // tile T+2 fully landed
    G_BAR2();
  }

  // epilogue: C/D layout col=lane&15, row=(lane>>4)*4+reg
  float bv[4];
#pragma unroll
  for (int g = 0; g < 4; ++g) bv[g] = bias[n0 + (4 * g + wn) * 16 + lm];
#pragma unroll
  for (int f = 0; f < 8; ++f) {
    const long mr = m0 + (2 * f + wm) * 16 + kq * 4;
#pragma unroll
    for (int g = 0; g < 4; ++g) {
      float* cp = C + mr * DIM + n0 + (4 * g + wn) * 16 + lm;
      cp[0]       = acc[f][g][0] + bv[g];
      cp[DIM]     = acc[f][g][1] + bv[g];
      cp[2 * DIM] = acc[f][g][2] + bv[g];
      cp[3 * DIM] = acc[f][g][3] + bv[g];
    }
  }
}

// ---------------- Fallback GEMM (fp32 A fused conversion) — unchanged ----------------
__global__ __launch_bounds__(256) void gemm_xw(const float* __restrict__ X,
                                               const __bf16* __restrict__ WT,
                                               const float* __restrict__ bias,
                                               float* __restrict__ C) {
  __shared__ __bf16 Asf[128 * 40];
  __shared__ __bf16 Bsf[128 * 32];

  const int tid = threadIdx.x;
  const int n0 = (blockIdx.x & 31) * 128;
  const int m0 = (blockIdx.x >> 5) * 128;

  const int wave = tid >> 6, lane = tid & 63;
  const int wm = (wave >> 1) * 64, wn = (wave & 1) * 64;
  const int lm = lane & 15, kq = lane >> 4;

  floatx4 acc[4][4] = {};

  const int ar = tid >> 1;
  const int ac = (tid & 1) * 16;
  const float* xp = X + (long)(m0 + ar) * DIM + ac;
  __bf16* as_dst = &Asf[ar * 40 + ac];

  const int u0 = tid, u1 = 256 + tid;
  const int r0 = u0 >> 2, r1 = u1 >> 2;
  const int ch0 = (u0 & 3) ^ (r0 & 3), ch1 = (u1 & 3) ^ (r1 & 3);
  const __bf16* wp0 = WT + (long)(n0 + r0) * DIM + ch0 * 8;
  const __bf16* wp1 = WT + (long)(n0 + r1) * DIM + ch1 * 8;

  float4 a0 = *(const float4*)(xp);
  float4 a1 = *(const float4*)(xp + 4);
  float4 a2 = *(const float4*)(xp + 8);
  float4 a3 = *(const float4*)(xp + 12);

#pragma unroll 1
  for (int k0 = 0; k0 < DIM; k0 += 32) {
    async_ld16(&Bsf[u0 * 8], wp0 + k0);
    async_ld16(&Bsf[u1 * 8], wp1 + k0);

    bf16x8 w0, w1;
    w0[0] = (__bf16)a0.x; w0[1] = (__bf16)a0.y; w0[2] = (__bf16)a0.z; w0[3] = (__bf16)a0.w;
    w0[4] = (__bf16)a1.x; w0[5] = (__bf16)a1.y; w0[6] = (__bf16)a1.z; w0[7] = (__bf16)a1.w;
    w1[0] = (__bf16)a2.x; w1[1] = (__bf16)a2.y; w1[2] = (__bf16)a2.z; w1[3] = (__bf16)a2.w;
    w1[4] = (__bf16)a3.x; w1[5] = (__bf16)a3.y; w1[6] = (__bf16)a3.z; w1[7] = (__bf16)a3.w;
    *(bf16x8*)(as_dst) = w0;
    *(bf16x8*)(as_dst + 8) = w1;

    if (k0 + 32 < DIM) {
      a0 = *(const float4*)(xp + k0 + 32);
      a1 = *(const float4*)(xp + k0 + 36);
      a2 = *(const float4*)(xp + k0 + 40);
      a3 = *(const float4*)(xp + k0 + 44);
    }
    __syncthreads();

    bf16x8 afv[4], bfr[4];
#pragma unroll
    for (int mi = 0; mi < 4; ++mi)
      afv[mi] = *(const bf16x8*)&Asf[(wm + mi * 16 + lm) * 40 + kq * 8];
#pragma unroll
    for (int ni = 0; ni < 4; ++ni) {
      int rr = wn + ni * 16 + lm;
      bfr[ni] = *(const bf16x8*)&Bsf[rr * 32 + ((kq ^ (rr & 3)) * 8)];
    }
#pragma unroll
    for (int mi = 0; mi < 4; ++mi)
#pragma unroll
      for (int ni = 0; ni < 4; ++ni)
        acc[mi][ni] = __builtin_amdgcn_mfma_f32_16x16x32_bf16(afv[mi], bfr[ni], acc[mi][ni], 0, 0, 0);
    __syncthreads();
  }

  float bv[4];
#pragma unroll
  for (int ni = 0; ni < 4; ++ni) bv[ni] = bias[n0 + wn + ni * 16 + lm];
#pragma unroll
  for (int mi = 0; mi < 4; ++mi) {
    long mr = m0 + wm + mi * 16 + kq * 4;
#pragma unroll
    for (int ni = 0; ni < 4; ++ni) {
      float* cp = C + mr * DIM + (n0 + wn + ni * 16 + lm);
      cp[0]       = acc[mi][ni][0] + bv[ni];
      cp[DIM]     = acc[mi][ni][1] + bv[ni];
      cp[2 * DIM] = acc[mi][ni][2] + bv[ni];
      cp[3 * DIM] = acc[mi][ni][3] + bv[ni];
    }
  }
}

extern "C" void kernel_launch(void* const* d_in, const int* in_sizes, int n_in,
                              void* d_out, int out_size, void* d_ws, size_t ws_size,
                              hipStream_t stream) {
  const float* x    = (const float*)d_in[0];
  const float* c0   = (const float*)d_in[1];
  const float* c1   = (const float*)d_in[2];
  const float* c2   = (const float*)d_in[3];
  const float* c3   = (const float*)d_in[4];
  const float* c4   = (const float*)d_in[5];
  const float* bias = (const float*)d_in[6];
  float* out = (float*)d_out;

  const size_t XB_SZ = 67108864;    // 8192*4096 bf16
  const size_t WT_SZ = 33554432;    // 4096*4096 bf16
  const size_t K012_SZ = 524288;    // 128*8*128 fp32
  const size_t K34_SZ = 32768;      // 8*32*32 fp32
  char* ws = (char*)d_ws;

  if (ws_size >= XB_SZ + WT_SZ + K012_SZ + K34_SZ) {
    __bf16* Xb  = (__bf16*)ws;
    __bf16* WT  = (__bf16*)(ws + XB_SZ);
    float* K012 = (float*)(ws + XB_SZ + WT_SZ);
    float* K34T = (float*)(ws + XB_SZ + WT_SZ + K012_SZ);

    build_k<<<544, 256, 0, stream>>>(c0, c1, c2, c3, c4, K012, K34T);
    build_wt_conv<<<24576, 256, 0, stream>>>(K012, K34T, WT, x, Xb);
    gemm_8ph<<<512, 512, 0, stream>>>(Xb, WT, bias, out);
  } else {
    __bf16* WT  = (__bf16*)ws;
    float* K012 = (float*)(ws + WT_SZ);
    float* K34T = (float*)(ws + WT_SZ + K012_SZ);

    build_k<<<544, 256, 0, stream>>>(c0, c1, c2, c3, c4, K012, K34T);
    build_wt_conv<<<8192, 256, 0, stream>>>(K012, K34T, WT, x, (__bf16*)nullptr);
    gemm_xw<<<2048, 256, 0, stream>>>(x, WT, bias, out);
  }
}